// Round 2
// baseline (113.720 us; speedup 1.0000x reference)
//
#include <hip/hip_runtime.h>
#include <hip/hip_bf16.h>

// TripletLoss: fused E·E^T + masked row min/max reduction. B=8192, D=256.
// dist = sqrt(2-2*sim) monotone decreasing in sim =>
//   dist_ap = dist(min sim over positives), dist_an = dist(max sim over negatives).
//
// R6: SYMMETRY. sim is symmetric, and min/max folds tolerate redundant coverage.
// Grid = 528 upper-triangle 256x256 unit pairs (bi <= bu). Each tile S[I,J] updates
// rows I (row-fold over cols, as before) AND rows J (col-fold over rows, new):
// per-element candidates pv = same? s:+inf, nv = same? -inf:s feed both folds.
// Col partials: in-lane over (ms,r), cross-quad shfl, LDS atomics into a 256-entry
// per-block array (stored as s+2 => positive => int-ordered atomics valid), flushed
// to global once per block. Waves skip compute (not barriers) for tiles strictly
// below their rows in diagonal blocks (covered by the transposed element).
// Pipeline from R5 kept: triple-buffered LDS, counted vmcnt, setprio.

#define BDIM 8192
#define DDIM 256

typedef short bf16x8 __attribute__((ext_vector_type(8)));
typedef float f32x4  __attribute__((ext_vector_type(4)));
typedef unsigned short u16;

static __device__ __forceinline__ bf16x8 ld_frag(const u16* p) {
    return *reinterpret_cast<const bf16x8*>(p);
}

static __device__ __forceinline__ u16 f2bf(float f) {
    union { float f; unsigned int u; } x; x.f = f;
    unsigned int u = x.u;
    unsigned int r = u + 0x7fffu + ((u >> 16) & 1u);  // RNE
    return (u16)(r >> 16);
}

static __device__ __forceinline__ void gload_lds16(const u16* g, u16* l) {
    __builtin_amdgcn_global_load_lds(
        (const __attribute__((address_space(1))) unsigned int*)g,
        (__attribute__((address_space(3))) unsigned int*)l, 16, 0, 0);
}

// ---- kernel 1: fp32 -> bf16 convert + init reduction arrays ----
__global__ __launch_bounds__(256) void cvt_init_kernel(const float* __restrict__ in,
                                                       u16* __restrict__ out,
                                                       int* __restrict__ minpos,
                                                       int* __restrict__ maxneg) {
    int i = blockIdx.x * 256 + threadIdx.x;          // 524288 threads, 4 elems each
    const float4 v = reinterpret_cast<const float4*>(in)[i];
    ushort4 o;
    o.x = f2bf(v.x); o.y = f2bf(v.y); o.z = f2bf(v.z); o.w = f2bf(v.w);
    reinterpret_cast<ushort4*>(out)[i] = o;
    if (i < BDIM) {
        minpos[i] = 0x7f800000;                      // +inf  (min over positives of sim+2)
        maxneg[i] = 0;                               // 0.0f  (max over negatives of sim+2)
    }
}

// ---- kernel 2: fused GEMM + masked row/col min/max over upper-triangle tiles ----
// block = 256 thr = 4 waves; wave w owns rows [bi*256 + w*64, +64) (ms=4).
// Block sweeps 256 cols (unit bu), 32 at a time; B-tile 32x256 bf16 = 16KB,
// triple-buffered, staged with global_load_lds w16; swizzle chunk c of row r
// at position c^(r&7) applied on the GLOBAL source address.
__global__ __launch_bounds__(256, 2) void triplet_main(const u16* __restrict__ Ebf,
                                                       const int* __restrict__ labels,
                                                       int* __restrict__ minpos,
                                                       int* __restrict__ maxneg) {
    __shared__ __align__(16) u16 smem[3][32 * DDIM];  // 3 x 16 KB
    __shared__ int slab[256];                         // block's column labels
    __shared__ int colmin[256], colmax[256];          // col-side partials (s+2 domain)

    const int tid  = threadIdx.x;
    const int w    = tid >> 6;
    const int l    = tid & 63;
    const int quad = l >> 4;
    const int r16  = l & 15;

    // decode linear block id -> (bi, bu), bu >= bi, 32 row units
    int t = blockIdx.x, bi = 0;
    while (t >= 32 - bi) { t -= 32 - bi; ++bi; }
    const int bu = bi + t;

    const int mblk  = bi * 256 + w * 64;             // wave's first row
    const int nbase = bu * 256;

    // stage the 256 column labels + init col partials (synced by first loop barrier)
    slab[tid]   = labels[nbase + tid];
    colmin[tid] = 0x7f800000;                        // +inf
    colmax[tid] = 0;                                 // 0.0f

    // Preload A fragments: a[ms][k] covers rows [mblk+ms*16,+16), k-chunk [k*32,+32)
    bf16x8 a[4][8];
#pragma unroll
    for (int ms = 0; ms < 4; ++ms) {
        const u16* ap = Ebf + (size_t)(mblk + ms * 16 + r16) * DDIM + quad * 8;
#pragma unroll
        for (int k = 0; k < 8; ++k) a[ms][k] = ld_frag(ap + k * 32);
    }

    int lab_row[4][4];
#pragma unroll
    for (int ms = 0; ms < 4; ++ms)
#pragma unroll
        for (int r = 0; r < 4; ++r)
            lab_row[ms][r] = labels[mblk + ms * 16 + quad * 4 + r];

    float minp[4][4], maxn[4][4];
#pragma unroll
    for (int ms = 0; ms < 4; ++ms)
#pragma unroll
        for (int r = 0; r < 4; ++r) { minp[ms][r] = __builtin_inff(); maxn[ms][r] = -__builtin_inff(); }

    // swizzled-read lane constants
    const int qs = quad ^ (r16 & 3);                 // low-2-bit chunk index after swizzle
    const int s4 = (r16 >> 2) & 1;                   // bit-2 of swizzle

    // stage tile tt (32 rows x 512B, swizzled on global source) into buffer buf
    auto stage = [&](int tt, int buf) {
        const int n1 = nbase + tt * 32;
#pragma unroll
        for (int it = 0; it < 4; ++it) {
            const int q = it * 256 + tid;
            const int r = q >> 5;
            const int c = (q & 31) ^ (r & 7);
            gload_lds16(Ebf + ((size_t)(n1 + r) << 8) + c * 8,
                        &smem[buf][0] + it * 2048 + w * 512);
        }
    };

    // prologue: prefetch tiles 0 and 1 (8 gload_lds outstanding)
    stage(0, 0);
    stage(1, 1);

    int cur = 0;                                     // buffer holding tile nn
#pragma unroll 1
    for (int nn = 0; nn < 8; ++nn) {
        // Counted wait: retire tile nn's 4 loads (oldest), leave tile nn+1's 4 in
        // flight. lgkmcnt(0) drains our ds_reads of the buffer that the post-barrier
        // stage() below will overwrite.
        if (nn < 7) asm volatile("s_waitcnt vmcnt(4) lgkmcnt(0)" ::: "memory");
        else        asm volatile("s_waitcnt vmcnt(0) lgkmcnt(0)" ::: "memory");
        __builtin_amdgcn_s_barrier();
        __builtin_amdgcn_sched_barrier(0);           // no hoisting above barrier

        if (nn + 2 < 8) {
            const int stg = (cur >= 1) ? cur - 1 : 2;
            stage(nn + 2, stg);
        }

        const int n0 = nbase + nn * 32;

        // diag blocks: tiles strictly below this wave's rows are covered by the
        // transposed element elsewhere in this block -> skip compute, keep barriers.
        if (n0 + 32 > mblk) {
            int lab_c[2];
            lab_c[0] = slab[nn * 32 + r16];
            lab_c[1] = slab[nn * 32 + 16 + r16];

            f32x4 acc[4][2];
#pragma unroll
            for (int ms = 0; ms < 4; ++ms)
#pragma unroll
                for (int nt = 0; nt < 2; ++nt)
                    acc[ms][nt] = (f32x4){0.f, 0.f, 0.f, 0.f};

            const u16* bb = &smem[cur][0];
            const u16* bnt[2];
#pragma unroll
            for (int nt = 0; nt < 2; ++nt)
                bnt[nt] = bb + (nt * 16 + r16) * DDIM + qs * 8;

            __builtin_amdgcn_s_setprio(1);
#pragma unroll
            for (int k = 0; k < 8; ++k) {
                const int koff = ((k ^ s4) << 5);
                bf16x8 b[2];
#pragma unroll
                for (int nt = 0; nt < 2; ++nt) b[nt] = ld_frag(bnt[nt] + koff);
#pragma unroll
                for (int ms = 0; ms < 4; ++ms)
#pragma unroll
                    for (int nt = 0; nt < 2; ++nt)
                        acc[ms][nt] = __builtin_amdgcn_mfma_f32_16x16x32_bf16(
                            a[ms][k], b[nt], acc[ms][nt], 0, 0, 0);
            }
            __builtin_amdgcn_s_setprio(0);

            // masked fold: row-side into minp/maxn, col-side into cmin/cmax.
            float cmin[2], cmax[2];
#pragma unroll
            for (int nt = 0; nt < 2; ++nt) { cmin[nt] = __builtin_inff(); cmax[nt] = -__builtin_inff(); }

            const bool diagTile = (n0 < mblk + 64) && (mblk < n0 + 32);
            if (__builtin_expect(diagTile, 0)) {
#pragma unroll
                for (int nt = 0; nt < 2; ++nt) {
                    const int colg = n0 + nt * 16 + r16;
#pragma unroll
                    for (int ms = 0; ms < 4; ++ms)
#pragma unroll
                        for (int r = 0; r < 4; ++r) {
                            const int rowg = mblk + ms * 16 + quad * 4 + r;
                            const float s = acc[ms][nt][r];
                            const bool same = (lab_c[nt] == lab_row[ms][r]);
                            const bool pos  = same && (colg != rowg);
                            const float pv = pos  ?  s : __builtin_inff();
                            const float nv = same ? -__builtin_inff() : s;
                            minp[ms][r] = fminf(minp[ms][r], pv);
                            maxn[ms][r] = fmaxf(maxn[ms][r], nv);
                            cmin[nt] = fminf(cmin[nt], pv);
                            cmax[nt] = fmaxf(cmax[nt], nv);
                        }
                }
            } else {
#pragma unroll
                for (int nt = 0; nt < 2; ++nt)
#pragma unroll
                    for (int ms = 0; ms < 4; ++ms)
#pragma unroll
                        for (int r = 0; r < 4; ++r) {
                            const float s = acc[ms][nt][r];
                            const bool same = (lab_c[nt] == lab_row[ms][r]);
                            const float pv = same ?  s : __builtin_inff();
                            const float nv = same ? -__builtin_inff() : s;
                            minp[ms][r] = fminf(minp[ms][r], pv);
                            maxn[ms][r] = fmaxf(maxn[ms][r], nv);
                            cmin[nt] = fminf(cmin[nt], pv);
                            cmax[nt] = fmaxf(cmax[nt], nv);
                        }
            }

            // col partials: reduce across quads (lane strides 16, 32), then LDS atomic
#pragma unroll
            for (int mask = 16; mask <= 32; mask <<= 1) {
#pragma unroll
                for (int nt = 0; nt < 2; ++nt) {
                    cmin[nt] = fminf(cmin[nt], __shfl_xor(cmin[nt], mask, 64));
                    cmax[nt] = fmaxf(cmax[nt], __shfl_xor(cmax[nt], mask, 64));
                }
            }
            if (quad == 0) {
#pragma unroll
                for (int nt = 0; nt < 2; ++nt) {
                    const int cl = nn * 32 + nt * 16 + r16;
                    atomicMin(&colmin[cl], __float_as_int(cmin[nt] + 2.0f));
                    atomicMax(&colmax[cl], __float_as_int(cmax[nt] + 2.0f));
                }
            }
        }

        cur = (cur == 2) ? 0 : cur + 1;
    }

    // row-side: reduce across the 16 lanes sharing a quad (same rows, different cols)
#pragma unroll
    for (int mask = 1; mask <= 8; mask <<= 1) {
#pragma unroll
        for (int ms = 0; ms < 4; ++ms)
#pragma unroll
            for (int r = 0; r < 4; ++r) {
                minp[ms][r] = fminf(minp[ms][r], __shfl_xor(minp[ms][r], mask, 64));
                maxn[ms][r] = fmaxf(maxn[ms][r], __shfl_xor(maxn[ms][r], mask, 64));
            }
    }
    if (r16 == 0) {
#pragma unroll
        for (int ms = 0; ms < 4; ++ms)
#pragma unroll
            for (int r = 0; r < 4; ++r) {
                const int rowg = mblk + ms * 16 + quad * 4 + r;
                atomicMin(minpos + rowg, __float_as_int(minp[ms][r] + 2.0f));
                atomicMax(maxneg + rowg, __float_as_int(maxn[ms][r] + 2.0f));
            }
    }

    // col-side: flush block partials (already in s+2 int domain)
    __syncthreads();
    atomicMin(minpos + nbase + tid, colmin[tid]);
    atomicMax(maxneg + nbase + tid, colmax[tid]);
}

// ---- kernel 3: finalize (single block, 1024 threads) ----
__global__ __launch_bounds__(1024) void finalize_kernel(const int* __restrict__ minpos,
                                                        const int* __restrict__ maxneg,
                                                        float* __restrict__ out) {
    __shared__ float ssum[16], scnt[16];
    float sum = 0.f, cnt = 0.f;
#pragma unroll
    for (int it = 0; it < 8; ++it) {
        const int i = it * 1024 + threadIdx.x;
        const float mp = __int_as_float(minpos[i]);  // min(sim)+2 over positives; +inf if none
        const float mn = __int_as_float(maxneg[i]);  // max(sim)+2 over negatives; 0 if none
        if (mp < 1e30f && mn > 0.5f) {
            // dist = sqrt(2 - 2*sim), sim = stored - 2  =>  2 - 2*(stored-2) = 6 - 2*stored
            const float dap = sqrtf(fmaxf(6.0f - 2.0f * mp, 0.0f) + 1e-12f);
            const float dan = sqrtf(fmaxf(6.0f - 2.0f * mn, 0.0f) + 1e-12f);
            sum += fmaxf(dap - dan + 0.3f, 0.0f);
            cnt += 1.0f;
        }
    }
#pragma unroll
    for (int off = 32; off > 0; off >>= 1) {
        sum += __shfl_down(sum, off, 64);
        cnt += __shfl_down(cnt, off, 64);
    }
    const int wid = threadIdx.x >> 6;
    if ((threadIdx.x & 63) == 0) { ssum[wid] = sum; scnt[wid] = cnt; }
    __syncthreads();
    if (threadIdx.x == 0) {
        float S = 0.f, C = 0.f;
#pragma unroll
        for (int i = 0; i < 16; ++i) { S += ssum[i]; C += scnt[i]; }
        out[0] = (C > 0.f) ? (S / C) : 0.f;
    }
}

extern "C" void kernel_launch(void* const* d_in, const int* in_sizes, int n_in,
                              void* d_out, int out_size, void* d_ws, size_t ws_size,
                              hipStream_t stream) {
    const float* emb    = (const float*)d_in[0];
    const int*   labels = (const int*)d_in[1];
    float*       out    = (float*)d_out;

    u16* Ebf    = (u16*)d_ws;                                  // 4 MB
    int* minpos = (int*)((char*)d_ws + (size_t)BDIM * DDIM * 2);
    int* maxneg = minpos + BDIM;

    cvt_init_kernel<<<dim3((BDIM * DDIM / 4) / 256), dim3(256), 0, stream>>>(emb, Ebf, minpos, maxneg);
    triplet_main<<<dim3(528), dim3(256), 0, stream>>>(Ebf, labels, minpos, maxneg);
    finalize_kernel<<<dim3(1), dim3(1024), 0, stream>>>(minpos, maxneg, out);
}

// Round 3
// 110.535 us; speedup vs baseline: 1.0288x; 1.0288x over previous
//
#include <hip/hip_runtime.h>
#include <hip/hip_bf16.h>

// TripletLoss: fused E·E^T + masked row min/max reduction. B=8192, D=256.
// dist = sqrt(2-2*sim) monotone decreasing in sim =>
//   dist_ap = dist(min sim over positives), dist_an = dist(max sim over negatives).
//
// R7: R6's symmetric (upper-triangle pair) coverage, rebalanced. R6's 528-block grid
// exceeded the 512-block co-residency (2 blocks/CU) by 16 -> serial tail doubled the
// duration. R7 flattens the 528 pairs x 8 col-tiles = 4224 tile-tasks over exactly
// 512 blocks (blocks 0-127: 9 tasks, 128-511: 8). A chunk spans <=2 pairs; on the
// (at most one) mid-block pair switch we flush col partials (iff bu changes), flush
// row accumulators + reload A (iff bi changes), reload the label slab, one extra
// barrier. The triple-buffered counted-vmcnt pipeline is slot-indexed and runs
// uninterrupted across the switch.

#define BDIM 8192
#define DDIM 256

typedef short bf16x8 __attribute__((ext_vector_type(8)));
typedef float f32x4  __attribute__((ext_vector_type(4)));
typedef unsigned short u16;

static __device__ __forceinline__ bf16x8 ld_frag(const u16* p) {
    return *reinterpret_cast<const bf16x8*>(p);
}

static __device__ __forceinline__ u16 f2bf(float f) {
    union { float f; unsigned int u; } x; x.f = f;
    unsigned int u = x.u;
    unsigned int r = u + 0x7fffu + ((u >> 16) & 1u);  // RNE
    return (u16)(r >> 16);
}

static __device__ __forceinline__ void gload_lds16(const u16* g, u16* l) {
    __builtin_amdgcn_global_load_lds(
        (const __attribute__((address_space(1))) unsigned int*)g,
        (__attribute__((address_space(3))) unsigned int*)l, 16, 0, 0);
}

// ---- kernel 1: fp32 -> bf16 convert + init reduction arrays ----
__global__ __launch_bounds__(256) void cvt_init_kernel(const float* __restrict__ in,
                                                       u16* __restrict__ out,
                                                       int* __restrict__ minpos,
                                                       int* __restrict__ maxneg) {
    int i = blockIdx.x * 256 + threadIdx.x;          // 524288 threads, 4 elems each
    const float4 v = reinterpret_cast<const float4*>(in)[i];
    ushort4 o;
    o.x = f2bf(v.x); o.y = f2bf(v.y); o.z = f2bf(v.z); o.w = f2bf(v.w);
    reinterpret_cast<ushort4*>(out)[i] = o;
    if (i < BDIM) {
        minpos[i] = 0x7f800000;                      // +inf  (min over positives of sim+2)
        maxneg[i] = 0;                               // 0.0f  (max over negatives of sim+2)
    }
}

// ---- kernel 2: fused GEMM + masked row/col min/max over flattened triangle tasks ----
__global__ __launch_bounds__(256, 2) void triplet_main(const u16* __restrict__ Ebf,
                                                       const int* __restrict__ labels,
                                                       int* __restrict__ minpos,
                                                       int* __restrict__ maxneg) {
    __shared__ __align__(16) u16 smem[3][32 * DDIM];  // 3 x 16 KB
    __shared__ int slab[256];                         // current pair's column labels
    __shared__ int colmin[256], colmax[256];          // col-side partials (s+2 domain)

    const int tid  = threadIdx.x;
    const int w    = tid >> 6;
    const int l    = tid & 63;
    const int quad = l >> 4;
    const int r16  = l & 15;

    // ---- task chunk: 4224 tasks over 512 blocks; blocks 0-127 get 9, rest get 8 ----
    const int blk   = blockIdx.x;
    const int start = blk * 8 + (blk < 128 ? blk : 128);
    const int count = (blk < 128) ? 9 : 8;
    const int pF    = start >> 3;
    const int pL    = (start + count - 1) >> 3;      // pF or pF+1

    int biF, buF, biL, buL;
    {
        int t = pF, b = 0;
        while (t >= 32 - b) { t -= 32 - b; ++b; }
        biF = b; buF = b + t;
    }
    {
        int t = pL, b = 0;
        while (t >= 32 - b) { t -= 32 - b; ++b; }
        biL = b; buL = b + t;
    }

    // shared init for first pair (covered by the first loop-head lgkmcnt+barrier)
    slab[tid]   = labels[buF * 256 + tid];
    colmin[tid] = 0x7f800000;                        // +inf
    colmax[tid] = 0;                                 // 0.0f

    // Register-resident A fragments + row labels for a given row unit bi
    bf16x8 a[4][8];
    int lab_row[4][4];
    auto loadA = [&](int bi) {
        const int mb = bi * 256 + w * 64;
#pragma unroll
        for (int ms = 0; ms < 4; ++ms) {
            const u16* ap = Ebf + (size_t)(mb + ms * 16 + r16) * DDIM + quad * 8;
#pragma unroll
            for (int k = 0; k < 8; ++k) a[ms][k] = ld_frag(ap + k * 32);
        }
#pragma unroll
        for (int ms = 0; ms < 4; ++ms)
#pragma unroll
            for (int r = 0; r < 4; ++r)
                lab_row[ms][r] = labels[mb + ms * 16 + quad * 4 + r];
    };
    loadA(biF);

    float minp[4][4], maxn[4][4];
    auto resetRC = [&]() {
#pragma unroll
        for (int ms = 0; ms < 4; ++ms)
#pragma unroll
            for (int r = 0; r < 4; ++r) { minp[ms][r] = __builtin_inff(); maxn[ms][r] = -__builtin_inff(); }
    };
    resetRC();

    auto flushRows = [&](int bi) {
        const int mb = bi * 256 + w * 64;
#pragma unroll
        for (int mask = 1; mask <= 8; mask <<= 1) {
#pragma unroll
            for (int ms = 0; ms < 4; ++ms)
#pragma unroll
                for (int r = 0; r < 4; ++r) {
                    minp[ms][r] = fminf(minp[ms][r], __shfl_xor(minp[ms][r], mask, 64));
                    maxn[ms][r] = fmaxf(maxn[ms][r], __shfl_xor(maxn[ms][r], mask, 64));
                }
        }
        if (r16 == 0) {
#pragma unroll
            for (int ms = 0; ms < 4; ++ms)
#pragma unroll
                for (int r = 0; r < 4; ++r) {
                    const int rowg = mb + ms * 16 + quad * 4 + r;
                    atomicMin(minpos + rowg, __float_as_int(minp[ms][r] + 2.0f));
                    atomicMax(maxneg + rowg, __float_as_int(maxn[ms][r] + 2.0f));
                }
        }
    };

    // swizzled-read lane constants
    const int qs = quad ^ (r16 & 3);                 // low-2-bit chunk index after swizzle
    const int s4 = (r16 >> 2) & 1;                   // bit-2 of swizzle

    // stage task slot s (32 rows x 512B, swizzled on global source) into buffer buf
    auto stage = [&](int s, int buf) {
        const int T  = start + s;
        const int bu = ((T >> 3) == pF) ? buF : buL;
        const int n1 = bu * 256 + (T & 7) * 32;
#pragma unroll
        for (int it = 0; it < 4; ++it) {
            const int q = it * 256 + tid;
            const int r = q >> 5;
            const int c = (q & 31) ^ (r & 7);
            gload_lds16(Ebf + ((size_t)(n1 + r) << 8) + c * 8,
                        &smem[buf][0] + it * 2048 + w * 512);
        }
    };

    // prologue: prefetch slots 0 and 1 (8 gload_lds outstanding); count >= 8 always
    stage(0, 0);
    stage(1, 1);

    int cur = 0;                                     // buffer holding slot s
    int curPair = pF;
#pragma unroll 1
    for (int s = 0; s < count; ++s) {
        const int T  = start + s;
        const int p  = T >> 3;
        const int nn = T & 7;

        // Counted wait: retire slot s's 4 loads, leave slot s+1's in flight.
        // lgkmcnt(0) drains our ds_reads + LDS atomics before buffer reuse / flush.
        if (s + 1 < count) asm volatile("s_waitcnt vmcnt(4) lgkmcnt(0)" ::: "memory");
        else               asm volatile("s_waitcnt vmcnt(0) lgkmcnt(0)" ::: "memory");
        __builtin_amdgcn_s_barrier();
        __builtin_amdgcn_sched_barrier(0);           // no hoisting above barrier

        if (p != curPair) {
            // Pair switch (uniform across waves; at most once per block).
            // All LDS atomics through s-1 are drained (lgkmcnt(0)) and all waves
            // passed the barrier above -> colmin/colmax stable.
            if (buL != buF) {
                atomicMin(minpos + buF * 256 + tid, colmin[tid]);
                atomicMax(maxneg + buF * 256 + tid, colmax[tid]);
                colmin[tid] = 0x7f800000;
                colmax[tid] = 0;
                slab[tid] = labels[buL * 256 + tid];
            }
            if (biL != biF) {
                flushRows(biF);
                resetRC();
                loadA(biL);
            }
            asm volatile("s_waitcnt lgkmcnt(0)" ::: "memory");  // slab/colmin writes done
            __builtin_amdgcn_s_barrier();            // resets visible before new atomics
            __builtin_amdgcn_sched_barrier(0);
            curPair = p;
        }

        if (s + 2 < count) {
            const int stg = (cur >= 1) ? cur - 1 : 2;
            stage(s + 2, stg);
        }

        const int bi   = (p == pF) ? biF : biL;
        const int bu   = (p == pF) ? buF : buL;
        const int mblk = bi * 256 + w * 64;
        const int n0   = bu * 256 + nn * 32;

        // diag pairs: tiles strictly below this wave's rows are covered by the
        // transposed element (col-fold of another wave/block) -> skip compute.
        if (n0 + 32 > mblk) {
            int lab_c[2];
            lab_c[0] = slab[nn * 32 + r16];
            lab_c[1] = slab[nn * 32 + 16 + r16];

            f32x4 acc[4][2];
#pragma unroll
            for (int ms = 0; ms < 4; ++ms)
#pragma unroll
                for (int nt = 0; nt < 2; ++nt)
                    acc[ms][nt] = (f32x4){0.f, 0.f, 0.f, 0.f};

            const u16* bb = &smem[cur][0];
            const u16* bnt[2];
#pragma unroll
            for (int nt = 0; nt < 2; ++nt)
                bnt[nt] = bb + (nt * 16 + r16) * DDIM + qs * 8;

            __builtin_amdgcn_s_setprio(1);
#pragma unroll
            for (int k = 0; k < 8; ++k) {
                const int koff = ((k ^ s4) << 5);
                bf16x8 b[2];
#pragma unroll
                for (int nt = 0; nt < 2; ++nt) b[nt] = ld_frag(bnt[nt] + koff);
#pragma unroll
                for (int ms = 0; ms < 4; ++ms)
#pragma unroll
                    for (int nt = 0; nt < 2; ++nt)
                        acc[ms][nt] = __builtin_amdgcn_mfma_f32_16x16x32_bf16(
                            a[ms][k], b[nt], acc[ms][nt], 0, 0, 0);
            }
            __builtin_amdgcn_s_setprio(0);

            // masked fold: row-side into minp/maxn, col-side into cmin/cmax.
            float cmin[2], cmax[2];
#pragma unroll
            for (int nt = 0; nt < 2; ++nt) { cmin[nt] = __builtin_inff(); cmax[nt] = -__builtin_inff(); }

            const bool diagTile = (n0 < mblk + 64) && (mblk < n0 + 32);
            if (__builtin_expect(diagTile, 0)) {
#pragma unroll
                for (int nt = 0; nt < 2; ++nt) {
                    const int colg = n0 + nt * 16 + r16;
#pragma unroll
                    for (int ms = 0; ms < 4; ++ms)
#pragma unroll
                        for (int r = 0; r < 4; ++r) {
                            const int rowg = mblk + ms * 16 + quad * 4 + r;
                            const float s2 = acc[ms][nt][r];
                            const bool same = (lab_c[nt] == lab_row[ms][r]);
                            const bool pos  = same && (colg != rowg);
                            const float pv = pos  ?  s2 : __builtin_inff();
                            const float nv = same ? -__builtin_inff() : s2;
                            minp[ms][r] = fminf(minp[ms][r], pv);
                            maxn[ms][r] = fmaxf(maxn[ms][r], nv);
                            cmin[nt] = fminf(cmin[nt], pv);
                            cmax[nt] = fmaxf(cmax[nt], nv);
                        }
                }
            } else {
#pragma unroll
                for (int nt = 0; nt < 2; ++nt)
#pragma unroll
                    for (int ms = 0; ms < 4; ++ms)
#pragma unroll
                        for (int r = 0; r < 4; ++r) {
                            const float s2 = acc[ms][nt][r];
                            const bool same = (lab_c[nt] == lab_row[ms][r]);
                            const float pv = same ?  s2 : __builtin_inff();
                            const float nv = same ? -__builtin_inff() : s2;
                            minp[ms][r] = fminf(minp[ms][r], pv);
                            maxn[ms][r] = fmaxf(maxn[ms][r], nv);
                            cmin[nt] = fminf(cmin[nt], pv);
                            cmax[nt] = fmaxf(cmax[nt], nv);
                        }
            }

            // col partials: reduce across quads (lane strides 16, 32), then LDS atomic
#pragma unroll
            for (int mask = 16; mask <= 32; mask <<= 1) {
#pragma unroll
                for (int nt = 0; nt < 2; ++nt) {
                    cmin[nt] = fminf(cmin[nt], __shfl_xor(cmin[nt], mask, 64));
                    cmax[nt] = fmaxf(cmax[nt], __shfl_xor(cmax[nt], mask, 64));
                }
            }
            if (quad == 0) {
#pragma unroll
                for (int nt = 0; nt < 2; ++nt) {
                    const int cl = nn * 32 + nt * 16 + r16;
                    atomicMin(&colmin[cl], __float_as_int(cmin[nt] + 2.0f));
                    atomicMax(&colmax[cl], __float_as_int(cmax[nt] + 2.0f));
                }
            }
        }

        cur = (cur == 2) ? 0 : cur + 1;
    }

    // final flush: current pair is pL
    flushRows(biL);
    __syncthreads();                                 // all waves' LDS atomics visible
    atomicMin(minpos + buL * 256 + tid, colmin[tid]);
    atomicMax(maxneg + buL * 256 + tid, colmax[tid]);
}

// ---- kernel 3: finalize (single block, 1024 threads) ----
__global__ __launch_bounds__(1024) void finalize_kernel(const int* __restrict__ minpos,
                                                        const int* __restrict__ maxneg,
                                                        float* __restrict__ out) {
    __shared__ float ssum[16], scnt[16];
    float sum = 0.f, cnt = 0.f;
#pragma unroll
    for (int it = 0; it < 8; ++it) {
        const int i = it * 1024 + threadIdx.x;
        const float mp = __int_as_float(minpos[i]);  // min(sim)+2 over positives; +inf if none
        const float mn = __int_as_float(maxneg[i]);  // max(sim)+2 over negatives; 0 if none
        if (mp < 1e30f && mn > 0.5f) {
            // dist = sqrt(2 - 2*sim), sim = stored - 2  =>  2 - 2*(stored-2) = 6 - 2*stored
            const float dap = sqrtf(fmaxf(6.0f - 2.0f * mp, 0.0f) + 1e-12f);
            const float dan = sqrtf(fmaxf(6.0f - 2.0f * mn, 0.0f) + 1e-12f);
            sum += fmaxf(dap - dan + 0.3f, 0.0f);
            cnt += 1.0f;
        }
    }
#pragma unroll
    for (int off = 32; off > 0; off >>= 1) {
        sum += __shfl_down(sum, off, 64);
        cnt += __shfl_down(cnt, off, 64);
    }
    const int wid = threadIdx.x >> 6;
    if ((threadIdx.x & 63) == 0) { ssum[wid] = sum; scnt[wid] = cnt; }
    __syncthreads();
    if (threadIdx.x == 0) {
        float S = 0.f, C = 0.f;
#pragma unroll
        for (int i = 0; i < 16; ++i) { S += ssum[i]; C += scnt[i]; }
        out[0] = (C > 0.f) ? (S / C) : 0.f;
    }
}

extern "C" void kernel_launch(void* const* d_in, const int* in_sizes, int n_in,
                              void* d_out, int out_size, void* d_ws, size_t ws_size,
                              hipStream_t stream) {
    const float* emb    = (const float*)d_in[0];
    const int*   labels = (const int*)d_in[1];
    float*       out    = (float*)d_out;

    u16* Ebf    = (u16*)d_ws;                                  // 4 MB
    int* minpos = (int*)((char*)d_ws + (size_t)BDIM * DDIM * 2);
    int* maxneg = minpos + BDIM;

    cvt_init_kernel<<<dim3((BDIM * DDIM / 4) / 256), dim3(256), 0, stream>>>(emb, Ebf, minpos, maxneg);
    triplet_main<<<dim3(512), dim3(256), 0, stream>>>(Ebf, labels, minpos, maxneg);
    finalize_kernel<<<dim3(1), dim3(1024), 0, stream>>>(minpos, maxneg, out);
}